// Round 2
// baseline (790.657 us; speedup 1.0000x reference)
//
#include <hip/hip_runtime.h>
#include <cstdint>
#include <cstddef>

#define DIMC 384
#define DST  16
#define LLEN 4096
#define NB   4
#define PDIM 800   // 2*DIMC + 2*DST

__device__ __forceinline__ float softplus_f(float v) {
    if (v > 20.f) return v;
    return logf(1.f + __expf(v));
}

// C[m][n] = sum_k A[b][k][ml] * Wm[n][k] + bias[n]
// A layout: [NB][K=384][LLEN], m = b*LLEN + ml.
// EPI==0: proj epilogue (split x_in/delta/Bm/Cm, softplus on delta, transposed stores)
// EPI==1: out epilogue (store transposed to o_out[b][n][l])
template<int EPI>
__global__ __launch_bounds__(256)
void gemm_kernel(const float* __restrict__ A, const float* __restrict__ Wm,
                 const float* __restrict__ bias, const float* __restrict__ dt_bias,
                 float* __restrict__ o_x, float* __restrict__ o_dt,
                 float* __restrict__ o_Bm, float* __restrict__ o_Cm,
                 float* __restrict__ o_out, int N)
{
    __shared__ float As[16][68];   // [k][m], +4 pad
    __shared__ float Bs[16][68];   // [k][n], +4 pad
    const int K   = DIMC;
    const int tid = threadIdx.x;
    const int tx  = tid & 15;      // n micro index
    const int ty  = tid >> 4;      // m micro index
    const int m0  = blockIdx.x * 64;
    const int n0  = blockIdx.y * 64;
    const int b   = m0 / LLEN;
    const int ml0 = m0 - b * LLEN;

    const int ka = tid >> 4;          // 0..15 (k row for A staging)
    const int ma = (tid & 15) * 4;    // m offset for A staging
    const int kb = tid & 15;          // k for B staging
    const int nb = (tid >> 4) * 4;    // n offset for B staging

    const float* Abase = A + ((size_t)b * K) * LLEN + ml0 + ma;

    float acc[4][4];
    #pragma unroll
    for (int i = 0; i < 4; ++i)
        #pragma unroll
        for (int j = 0; j < 4; ++j) acc[i][j] = 0.f;

    for (int k0 = 0; k0 < K; k0 += 16) {
        __syncthreads();
        // stage A tile (coalesced: 16 consecutive float4 per k-row)
        float4 av = *(const float4*)(Abase + (size_t)(k0 + ka) * LLEN);
        *(float4*)&As[ka][ma] = av;
        // stage B tile
        float bvv[4];
        #pragma unroll
        for (int i = 0; i < 4; ++i) {
            int n = n0 + nb + i;
            bvv[i] = (n < N) ? Wm[(size_t)n * K + (k0 + kb)] : 0.f;
        }
        *(float4*)&Bs[kb][nb] = *(float4*)bvv;
        __syncthreads();
        #pragma unroll
        for (int k = 0; k < 16; ++k) {
            float a_[4], b_[4];
            *(float4*)a_ = *(const float4*)&As[k][ty * 4];
            *(float4*)b_ = *(const float4*)&Bs[k][tx * 4];
            #pragma unroll
            for (int i = 0; i < 4; ++i)
                #pragma unroll
                for (int j = 0; j < 4; ++j)
                    acc[i][j] = fmaf(a_[i], b_[j], acc[i][j]);
        }
    }

    const int l = ml0 + ty * 4;
    if (EPI == 0) {
        #pragma unroll
        for (int j = 0; j < 4; ++j) {
            int n = n0 + tx * 4 + j;
            if (n >= PDIM) continue;
            float bb = bias[n];
            float v[4];
            #pragma unroll
            for (int i = 0; i < 4; ++i) v[i] = acc[i][j] + bb;
            if (n < DIMC) {
                float4 st; st.x = v[0]; st.y = v[1]; st.z = v[2]; st.w = v[3];
                *(float4*)(o_x + ((size_t)b * DIMC + n) * LLEN + l) = st;
            } else if (n < 2 * DIMC) {
                int d = n - DIMC;
                float db = dt_bias[d];
                #pragma unroll
                for (int i = 0; i < 4; ++i) v[i] = softplus_f(v[i] + db);
                float4 st; st.x = v[0]; st.y = v[1]; st.z = v[2]; st.w = v[3];
                *(float4*)(o_dt + ((size_t)b * DIMC + d) * LLEN + l) = st;
            } else if (n < 2 * DIMC + DST) {
                int s = n - 2 * DIMC;
                #pragma unroll
                for (int i = 0; i < 4; ++i)
                    o_Bm[((size_t)b * LLEN + l + i) * DST + s] = v[i];
            } else {
                int s = n - 2 * DIMC - DST;
                #pragma unroll
                for (int i = 0; i < 4; ++i)
                    o_Cm[((size_t)b * LLEN + l + i) * DST + s] = v[i];
            }
        }
    } else {
        #pragma unroll
        for (int j = 0; j < 4; ++j) {
            int n = n0 + tx * 4 + j;
            float bb = bias[n];
            float4 st;
            st.x = acc[0][j] + bb; st.y = acc[1][j] + bb;
            st.z = acc[2][j] + bb; st.w = acc[3][j] + bb;
            *(float4*)(o_out + ((size_t)b * DIMC + n) * LLEN + l) = st;
        }
    }
}

// One thread per (b, d, n): h-recurrence over t, 16-lane shfl reduce for y.
// dt_t/x_t/y_t layout: [b][d][t]; Bm/Cm layout: [b][t][16].
__global__ __launch_bounds__(256)
void scan_kernel(const float* __restrict__ dt_t, const float* __restrict__ x_t,
                 const float* __restrict__ Bm, const float* __restrict__ Cm,
                 const float* __restrict__ A_log, const float* __restrict__ Dv,
                 float* __restrict__ y_t)
{
    const int tid = threadIdx.x;
    const int n   = tid & 15;
    const int dl  = tid >> 4;                  // 0..15
    const int gid = blockIdx.x * 16 + dl;      // over [0, NB*DIMC)
    const int b   = gid / DIMC;
    const int d   = gid - b * DIMC;

    const float Aval = -__expf(A_log[d * DST + n]);
    const float Dd   = Dv[d];

    const float* dtp = dt_t + (size_t)gid * LLEN;
    const float* xp  = x_t  + (size_t)gid * LLEN;
    const float* Bp  = Bm + ((size_t)b * LLEN) * DST + n;
    const float* Cp  = Cm + ((size_t)b * LLEN) * DST + n;
    float*       yp  = y_t + (size_t)gid * LLEN;

    float h = 0.f;
    for (int t0 = 0; t0 < LLEN; t0 += 4) {
        float4 dt4 = *(const float4*)(dtp + t0);
        float4 x4  = *(const float4*)(xp + t0);
        float bv[4], cv[4];
        #pragma unroll
        for (int j = 0; j < 4; ++j) {
            bv[j] = Bp[(size_t)(t0 + j) * DST];
            cv[j] = Cp[(size_t)(t0 + j) * DST];
        }
        float dts[4] = {dt4.x, dt4.y, dt4.z, dt4.w};
        float xs[4]  = {x4.x, x4.y, x4.z, x4.w};
        float ys[4];
        #pragma unroll
        for (int j = 0; j < 4; ++j) {
            float a = __expf(dts[j] * Aval);
            h = fmaf(a, h, dts[j] * xs[j] * bv[j]);
            float p = h * cv[j];
            p += __shfl_xor(p, 1);
            p += __shfl_xor(p, 2);
            p += __shfl_xor(p, 4);
            p += __shfl_xor(p, 8);
            ys[j] = fmaf(xs[j], Dd, p);
        }
        if (n == 0) {
            float4 st; st.x = ys[0]; st.y = ys[1]; st.z = ys[2]; st.w = ys[3];
            *(float4*)(yp + t0) = st;
        }
    }
}

extern "C" void kernel_launch(void* const* d_in, const int* in_sizes, int n_in,
                              void* d_out, int out_size, void* d_ws, size_t ws_size,
                              hipStream_t stream)
{
    const float* x      = (const float*)d_in[0];
    const float* W_proj = (const float*)d_in[1];
    const float* b_proj = (const float*)d_in[2];
    const float* A_log  = (const float*)d_in[3];
    const float* Dv     = (const float*)d_in[4];
    const float* dt_b   = (const float*)d_in[5];
    const float* W_out  = (const float*)d_in[6];
    const float* b_out  = (const float*)d_in[7];
    float* out = (float*)d_out;
    float* ws  = (float*)d_ws;

    const size_t szBD = (size_t)NB * DIMC * LLEN;   // 6,291,456 floats
    const size_t szBC = (size_t)NB * LLEN * DST;    //   262,144 floats
    float* x_t  = ws;
    float* dt_t = x_t + szBD;
    float* Bmw  = dt_t + szBD;
    float* Cmw  = Bmw + szBC;
    float* y_t  = Cmw + szBC;   // total ~77.6 MB of ws

    dim3 g1((NB * LLEN) / 64, (PDIM + 63) / 64);
    gemm_kernel<0><<<g1, 256, 0, stream>>>(x, W_proj, b_proj, dt_b,
                                           x_t, dt_t, Bmw, Cmw, nullptr, PDIM);

    scan_kernel<<<(NB * DIMC) / 16, 256, 0, stream>>>(dt_t, x_t, Bmw, Cmw,
                                                      A_log, Dv, y_t);

    dim3 g2((NB * LLEN) / 64, DIMC / 64);
    gemm_kernel<1><<<g2, 256, 0, stream>>>(y_t, W_out, b_out, nullptr,
                                           nullptr, nullptr, nullptr, nullptr,
                                           out, DIMC);
}

// Round 3
// 404.131 us; speedup vs baseline: 1.9564x; 1.9564x over previous
//
#include <hip/hip_runtime.h>
#include <cstdint>
#include <cstddef>

#define DIMC 384
#define DST  16
#define LLEN 4096
#define NB   4
#define PDIM 800   // 2*DIMC + 2*DST
#define NCH  64    // chunks per sequence
#define CL   64    // chunk length (NCH*CL == LLEN)

__device__ __forceinline__ float softplus_f(float v) {
    if (v > 20.f) return v;
    return logf(1.f + __expf(v));
}

// C[m][n] = sum_k A[b][k][ml] * Wm[n][k] + bias[n]
// A layout: [NB][K=384][LLEN], m = b*LLEN + ml.
// EPI==0: proj epilogue (split x_in/delta/Bm/Cm, softplus on delta, transposed stores)
// EPI==1: out epilogue (store transposed to o_out[b][n][l])
template<int EPI>
__global__ __launch_bounds__(256)
void gemm_kernel(const float* __restrict__ A, const float* __restrict__ Wm,
                 const float* __restrict__ bias, const float* __restrict__ dt_bias,
                 float* __restrict__ o_x, float* __restrict__ o_dt,
                 float* __restrict__ o_Bm, float* __restrict__ o_Cm,
                 float* __restrict__ o_out, int N)
{
    __shared__ float As[16][68];   // [k][m], +4 pad
    __shared__ float Bs[16][68];   // [k][n], +4 pad
    const int K   = DIMC;
    const int tid = threadIdx.x;
    const int tx  = tid & 15;      // n micro index
    const int ty  = tid >> 4;      // m micro index
    const int m0  = blockIdx.x * 64;
    const int n0  = blockIdx.y * 64;
    const int b   = m0 / LLEN;
    const int ml0 = m0 - b * LLEN;

    const int ka = tid >> 4;          // 0..15 (k row for A staging)
    const int ma = (tid & 15) * 4;    // m offset for A staging
    const int kb = tid & 15;          // k for B staging
    const int nb = (tid >> 4) * 4;    // n offset for B staging

    const float* Abase = A + ((size_t)b * K) * LLEN + ml0 + ma;

    float acc[4][4];
    #pragma unroll
    for (int i = 0; i < 4; ++i)
        #pragma unroll
        for (int j = 0; j < 4; ++j) acc[i][j] = 0.f;

    for (int k0 = 0; k0 < K; k0 += 16) {
        __syncthreads();
        float4 av = *(const float4*)(Abase + (size_t)(k0 + ka) * LLEN);
        *(float4*)&As[ka][ma] = av;
        float bvv[4];
        #pragma unroll
        for (int i = 0; i < 4; ++i) {
            int n = n0 + nb + i;
            bvv[i] = (n < N) ? Wm[(size_t)n * K + (k0 + kb)] : 0.f;
        }
        *(float4*)&Bs[kb][nb] = *(float4*)bvv;
        __syncthreads();
        #pragma unroll
        for (int k = 0; k < 16; ++k) {
            float a_[4], b_[4];
            *(float4*)a_ = *(const float4*)&As[k][ty * 4];
            *(float4*)b_ = *(const float4*)&Bs[k][tx * 4];
            #pragma unroll
            for (int i = 0; i < 4; ++i)
                #pragma unroll
                for (int j = 0; j < 4; ++j)
                    acc[i][j] = fmaf(a_[i], b_[j], acc[i][j]);
        }
    }

    const int l = ml0 + ty * 4;
    if (EPI == 0) {
        #pragma unroll
        for (int j = 0; j < 4; ++j) {
            int n = n0 + tx * 4 + j;
            if (n >= PDIM) continue;
            float bb = bias[n];
            float v[4];
            #pragma unroll
            for (int i = 0; i < 4; ++i) v[i] = acc[i][j] + bb;
            if (n < DIMC) {
                float4 st; st.x = v[0]; st.y = v[1]; st.z = v[2]; st.w = v[3];
                *(float4*)(o_x + ((size_t)b * DIMC + n) * LLEN + l) = st;
            } else if (n < 2 * DIMC) {
                int d = n - DIMC;
                float db = dt_bias[d];
                #pragma unroll
                for (int i = 0; i < 4; ++i) v[i] = softplus_f(v[i] + db);
                float4 st; st.x = v[0]; st.y = v[1]; st.z = v[2]; st.w = v[3];
                *(float4*)(o_dt + ((size_t)b * DIMC + d) * LLEN + l) = st;
            } else if (n < 2 * DIMC + DST) {
                int s = n - 2 * DIMC;
                #pragma unroll
                for (int i = 0; i < 4; ++i)
                    o_Bm[((size_t)b * LLEN + l + i) * DST + s] = v[i];
            } else {
                int s = n - 2 * DIMC - DST;
                #pragma unroll
                for (int i = 0; i < 4; ++i)
                    o_Cm[((size_t)b * LLEN + l + i) * DST + s] = v[i];
            }
        }
    } else {
        #pragma unroll
        for (int j = 0; j < 4; ++j) {
            int n = n0 + tx * 4 + j;
            float bb = bias[n];
            float4 st;
            st.x = acc[0][j] + bb; st.y = acc[1][j] + bb;
            st.z = acc[2][j] + bb; st.w = acc[3][j] + bb;
            *(float4*)(o_out + ((size_t)b * DIMC + n) * LLEN + l) = st;
        }
    }
}

// ---- Chunked scan ----
// Pass 1: per (bd, chunk, n) compute chunk transfer coefficients:
//   h_out = P * h_in + q   with P = prod(a_t), q = local scan end (h_in = 0)
__global__ __launch_bounds__(256)
void scan_part1(const float* __restrict__ dt_t, const float* __restrict__ x_t,
                const float* __restrict__ Bm, const float* __restrict__ A_log,
                float* __restrict__ Pc, float* __restrict__ Qc)
{
    const int tid = threadIdx.x;
    const int n   = tid & 15;
    const int g   = blockIdx.x * 16 + (tid >> 4);  // over B*DIMC*NCH
    const int bd  = g >> 6;                        // / NCH
    const int chk = g & (NCH - 1);
    const int b   = bd / DIMC;
    const int d   = bd - b * DIMC;

    const float Aval = -__expf(A_log[d * DST + n]);
    const float* dtp = dt_t + (size_t)bd * LLEN + chk * CL;
    const float* xp  = x_t  + (size_t)bd * LLEN + chk * CL;
    const float* Bp  = Bm + ((size_t)b * LLEN + chk * CL) * DST + n;

    float P = 1.f, q = 0.f;
    for (int t0 = 0; t0 < CL; t0 += 4) {
        float4 dt4 = *(const float4*)(dtp + t0);
        float4 x4  = *(const float4*)(xp + t0);
        float bv[4];
        #pragma unroll
        for (int j = 0; j < 4; ++j) bv[j] = Bp[(size_t)(t0 + j) * DST];
        float dts[4] = {dt4.x, dt4.y, dt4.z, dt4.w};
        float xs[4]  = {x4.x, x4.y, x4.z, x4.w};
        #pragma unroll
        for (int j = 0; j < 4; ++j) {
            float a = __expf(dts[j] * Aval);
            P *= a;
            q = fmaf(a, q, dts[j] * xs[j] * bv[j]);
        }
    }
    Pc[(size_t)g * DST + n] = P;
    Qc[(size_t)g * DST + n] = q;
}

// Pass 2: serial composition over chunks -> h at each chunk start.
__global__ __launch_bounds__(256)
void scan_carry(const float* __restrict__ Pc, const float* __restrict__ Qc,
                float* __restrict__ Hin)
{
    const int idx = blockIdx.x * 256 + threadIdx.x;  // over B*DIMC*16
    const int bd  = idx >> 4;
    const int n   = idx & 15;
    float h = 0.f;
    for (int chk = 0; chk < NCH; ++chk) {
        size_t o = ((size_t)bd * NCH + chk) * DST + n;
        Hin[o] = h;
        h = fmaf(Pc[o], h, Qc[o]);
    }
}

// Pass 3: rerun local scan from correct h_in, produce y.
__global__ __launch_bounds__(256)
void scan_part3(const float* __restrict__ dt_t, const float* __restrict__ x_t,
                const float* __restrict__ Bm, const float* __restrict__ Cm,
                const float* __restrict__ A_log, const float* __restrict__ Dv,
                const float* __restrict__ Hin, float* __restrict__ y_t)
{
    const int tid = threadIdx.x;
    const int n   = tid & 15;
    const int g   = blockIdx.x * 16 + (tid >> 4);
    const int bd  = g >> 6;
    const int chk = g & (NCH - 1);
    const int b   = bd / DIMC;
    const int d   = bd - b * DIMC;

    const float Aval = -__expf(A_log[d * DST + n]);
    const float Dd   = Dv[d];
    const float* dtp = dt_t + (size_t)bd * LLEN + chk * CL;
    const float* xp  = x_t  + (size_t)bd * LLEN + chk * CL;
    const float* Bp  = Bm + ((size_t)b * LLEN + chk * CL) * DST + n;
    const float* Cp  = Cm + ((size_t)b * LLEN + chk * CL) * DST + n;
    float*       yp  = y_t + (size_t)bd * LLEN + chk * CL;

    float h = Hin[(size_t)g * DST + n];
    for (int t0 = 0; t0 < CL; t0 += 4) {
        float4 dt4 = *(const float4*)(dtp + t0);
        float4 x4  = *(const float4*)(xp + t0);
        float bv[4], cv[4];
        #pragma unroll
        for (int j = 0; j < 4; ++j) {
            bv[j] = Bp[(size_t)(t0 + j) * DST];
            cv[j] = Cp[(size_t)(t0 + j) * DST];
        }
        float dts[4] = {dt4.x, dt4.y, dt4.z, dt4.w};
        float xs[4]  = {x4.x, x4.y, x4.z, x4.w};
        float ys[4];
        #pragma unroll
        for (int j = 0; j < 4; ++j) {
            float a = __expf(dts[j] * Aval);
            h = fmaf(a, h, dts[j] * xs[j] * bv[j]);
            float p = h * cv[j];
            p += __shfl_xor(p, 1);
            p += __shfl_xor(p, 2);
            p += __shfl_xor(p, 4);
            p += __shfl_xor(p, 8);
            ys[j] = fmaf(xs[j], Dd, p);
        }
        if (n == 0) {
            float4 st; st.x = ys[0]; st.y = ys[1]; st.z = ys[2]; st.w = ys[3];
            *(float4*)(yp + t0) = st;
        }
    }
}

extern "C" void kernel_launch(void* const* d_in, const int* in_sizes, int n_in,
                              void* d_out, int out_size, void* d_ws, size_t ws_size,
                              hipStream_t stream)
{
    const float* x      = (const float*)d_in[0];
    const float* W_proj = (const float*)d_in[1];
    const float* b_proj = (const float*)d_in[2];
    const float* A_log  = (const float*)d_in[3];
    const float* Dv     = (const float*)d_in[4];
    const float* dt_b   = (const float*)d_in[5];
    const float* W_out  = (const float*)d_in[6];
    const float* b_out  = (const float*)d_in[7];
    float* out = (float*)d_out;
    float* ws  = (float*)d_ws;

    const size_t szBD = (size_t)NB * DIMC * LLEN;        // 6,291,456
    const size_t szBC = (size_t)NB * LLEN * DST;         //   262,144
    const size_t szPQ = (size_t)NB * DIMC * NCH * DST;   // 1,572,864
    float* x_t  = ws;
    float* dt_t = x_t + szBD;
    float* Bmw  = dt_t + szBD;
    float* Cmw  = Bmw + szBC;
    float* y_t  = Cmw + szBC;
    float* Pc   = y_t + szBD;
    float* Qc   = Pc + szPQ;
    float* Hin  = Qc + szPQ;   // total ~92 MB

    dim3 g1((NB * LLEN) / 64, (PDIM + 63) / 64);
    gemm_kernel<0><<<g1, 256, 0, stream>>>(x, W_proj, b_proj, dt_b,
                                           x_t, dt_t, Bmw, Cmw, nullptr, PDIM);

    const int ngroups = NB * DIMC * NCH;      // 98,304
    scan_part1<<<ngroups / 16, 256, 0, stream>>>(dt_t, x_t, Bmw, A_log, Pc, Qc);
    scan_carry<<<(NB * DIMC * DST) / 256, 256, 0, stream>>>(Pc, Qc, Hin);
    scan_part3<<<ngroups / 16, 256, 0, stream>>>(dt_t, x_t, Bmw, Cmw,
                                                 A_log, Dv, Hin, y_t);

    dim3 g2((NB * LLEN) / 64, DIMC / 64);
    gemm_kernel<1><<<g2, 256, 0, stream>>>(y_t, W_out, b_out, nullptr,
                                           nullptr, nullptr, nullptr, nullptr,
                                           out, DIMC);
}

// Round 4
// 248.706 us; speedup vs baseline: 3.1791x; 1.6249x over previous
//
#include <hip/hip_runtime.h>
#include <cstdint>
#include <cstddef>

#define DIMC 384
#define DST  16
#define LLEN 4096
#define NB   4
#define PDIM 800   // 2*DIMC + 2*DST
#define NCH  64
#define CL   64
#define KDIM 384

typedef __attribute__((ext_vector_type(8))) short bf16x8;
typedef __attribute__((ext_vector_type(4))) float f32x4;

#define GLOAD16(g, l) __builtin_amdgcn_global_load_lds( \
    (const __attribute__((address_space(1))) uint32_t*)(g), \
    (__attribute__((address_space(3))) uint32_t*)(l), 16, 0, 0)

__device__ __forceinline__ float softplus_f(float v) {
    if (v > 20.f) return v;
    return logf(1.f + __expf(v));
}

__device__ __forceinline__ ushort f2bf(float x) {
    uint32_t u = __float_as_uint(x);
    uint32_t r = (u + 0x7FFFu + ((u >> 16) & 1u)) >> 16;
    return (ushort)r;
}

// fp32 -> bf16 elementwise; i in [n_src, n_tot) writes zeros (pad rows).
__global__ __launch_bounds__(256)
void cast_bf(const float* __restrict__ in, ushort* __restrict__ out,
             int n_src, int n_tot)
{
    int i = (blockIdx.x * 256 + threadIdx.x) * 4;
    if (i >= n_tot) return;
    if (i < n_src) {
        float4 v = *(const float4*)(in + i);
        ushort4 s; s.x = f2bf(v.x); s.y = f2bf(v.y); s.z = f2bf(v.z); s.w = f2bf(v.w);
        *(ushort4*)(out + i) = s;
    } else {
        ushort4 s; s.x = 0; s.y = 0; s.z = 0; s.w = 0;
        *(ushort4*)(out + i) = s;
    }
}

// in: [B][R=384][C=4096] fp32 ; out: [B][C][R] bf16. 64x64 LDS tile.
__global__ __launch_bounds__(256)
void transpose_cast(const float* __restrict__ in, ushort* __restrict__ out)
{
    __shared__ float t[64][65];
    const int tid = threadIdx.x;
    const int b  = blockIdx.z;
    const int c0 = blockIdx.y * 64;
    const int l0 = blockIdx.x * 64;
    const float* ip = in + ((size_t)b * DIMC + c0) * LLEN + l0;
    #pragma unroll
    for (int r = 0; r < 4; ++r) {
        int cl = (tid >> 4) + r * 16;
        int l4 = (tid & 15) * 4;
        float4 v = *(const float4*)(ip + (size_t)cl * LLEN + l4);
        t[cl][l4 + 0] = v.x; t[cl][l4 + 1] = v.y;
        t[cl][l4 + 2] = v.z; t[cl][l4 + 3] = v.w;
    }
    __syncthreads();
    ushort* op = out + ((size_t)b * LLEN + l0) * DIMC + c0;
    #pragma unroll
    for (int r = 0; r < 4; ++r) {
        int ll = (tid >> 4) + r * 16;
        int c4 = (tid & 15) * 4;
        ushort4 s;
        s.x = f2bf(t[c4 + 0][ll]); s.y = f2bf(t[c4 + 1][ll]);
        s.z = f2bf(t[c4 + 2][ll]); s.w = f2bf(t[c4 + 3][ll]);
        *(ushort4*)(op + (size_t)ll * DIMC + c4) = s;
    }
}

// bf16 MFMA GEMM. A: [16384][384] bf16 (m-major). B: [Nrows][384] bf16 (n-major, K contig).
// C[m][n] = sum_k A[m][k]*B[n][k]. Tile 128(m) x 64(n), BK=32, 4 waves.
// EPI 0: proj epilogue; EPI 1: out epilogue (store [b][n][l] fp32 + bias).
template<int EPI>
__global__ __launch_bounds__(256)
void mfma_gemm(const ushort* __restrict__ Abf, const ushort* __restrict__ Wbf,
               const float* __restrict__ bias, const float* __restrict__ dt_bias,
               float* __restrict__ o_x, float* __restrict__ o_dt,
               float* __restrict__ o_Bm, float* __restrict__ o_Cm,
               float* __restrict__ o_out)
{
    __shared__ ushort Alds[128 * 32];  // 8 KB, [row][32 k] with kgrp swizzle
    __shared__ ushort Blds[64 * 32];   // 4 KB

    const int tid = threadIdx.x;
    const int m0  = blockIdx.x * 128;
    const int n0  = blockIdx.y * 64;
    const int w   = tid >> 6;        // wave 0..3
    const int ln  = tid & 63;
    const int wm  = w * 32;          // wave row base within tile
    const int fr  = ln & 15;         // fragment row/col
    const int fg  = ln >> 4;         // k-group 0..3

    const int srow = tid >> 2;       // 0..63 staging row
    const int sg   = tid & 3;        // staging k-group slot

    const ushort* Ag = Abf + (size_t)m0 * KDIM;
    const ushort* Bg = Wbf + (size_t)n0 * KDIM;

    f32x4 acc[2][4];
    #pragma unroll
    for (int i = 0; i < 2; ++i)
        #pragma unroll
        for (int j = 0; j < 4; ++j)
            acc[i][j] = (f32x4){0.f, 0.f, 0.f, 0.f};

    for (int k0 = 0; k0 < KDIM; k0 += 32) {
        if (k0) __syncthreads();
        // stage A (two 64-row halves) + B, kgrp pre-swizzled at the SOURCE
        {
            int a0 = sg ^ ((srow >> 1) & 3);
            GLOAD16(Ag + (size_t)srow * KDIM + k0 + a0 * 8, &Alds[tid * 8]);
            int r1 = srow + 64;
            int a1 = sg ^ ((r1 >> 1) & 3);
            GLOAD16(Ag + (size_t)r1 * KDIM + k0 + a1 * 8, &Alds[2048 + tid * 8]);
            GLOAD16(Bg + (size_t)srow * KDIM + k0 + a0 * 8, &Blds[tid * 8]);
        }
        __syncthreads();
        bf16x8 af[2], bfv[4];
        #pragma unroll
        for (int i = 0; i < 2; ++i) {
            int r = wm + i * 16 + fr;
            af[i] = *(const bf16x8*)&Alds[r * 32 + ((fg ^ ((r >> 1) & 3)) << 3)];
        }
        #pragma unroll
        for (int j = 0; j < 4; ++j) {
            int r = j * 16 + fr;
            bfv[j] = *(const bf16x8*)&Blds[r * 32 + ((fg ^ ((r >> 1) & 3)) << 3)];
        }
        #pragma unroll
        for (int i = 0; i < 2; ++i)
            #pragma unroll
            for (int j = 0; j < 4; ++j)
                acc[i][j] = __builtin_amdgcn_mfma_f32_16x16x32_bf16(af[i], bfv[j], acc[i][j], 0, 0, 0);
    }

    // epilogue: C row = m0 + wm + i*16 + fg*4 + reg, col = n0 + j*16 + fr
    const int b   = m0 / LLEN;
    const int ml0 = m0 - b * LLEN;
    #pragma unroll
    for (int j = 0; j < 4; ++j) {
        const int n = n0 + j * 16 + fr;
        #pragma unroll
        for (int i = 0; i < 2; ++i) {
            const int l = ml0 + wm + i * 16 + fg * 4;
            f32x4 v = acc[i][j];
            if (EPI == 0) {
                if (n < DIMC) {
                    const float bb = bias[n];
                    float4 st; st.x = v[0] + bb; st.y = v[1] + bb; st.z = v[2] + bb; st.w = v[3] + bb;
                    *(float4*)(o_x + ((size_t)b * DIMC + n) * LLEN + l) = st;
                } else if (n < 2 * DIMC) {
                    const int d = n - DIMC;
                    const float bb = bias[n] + dt_bias[d];
                    float4 st;
                    st.x = softplus_f(v[0] + bb); st.y = softplus_f(v[1] + bb);
                    st.z = softplus_f(v[2] + bb); st.w = softplus_f(v[3] + bb);
                    *(float4*)(o_dt + ((size_t)b * DIMC + d) * LLEN + l) = st;
                } else if (n < 2 * DIMC + DST) {
                    const int s = n - 2 * DIMC;
                    const float bb = bias[n];
                    #pragma unroll
                    for (int r = 0; r < 4; ++r)
                        o_Bm[((size_t)b * LLEN + l + r) * DST + s] = v[r] + bb;
                } else if (n < PDIM) {
                    const int s = n - 2 * DIMC - DST;
                    const float bb = bias[n];
                    #pragma unroll
                    for (int r = 0; r < 4; ++r)
                        o_Cm[((size_t)b * LLEN + l + r) * DST + s] = v[r] + bb;
                }
            } else {
                const float bb = bias[n];
                float4 st; st.x = v[0] + bb; st.y = v[1] + bb; st.z = v[2] + bb; st.w = v[3] + bb;
                *(float4*)(o_out + ((size_t)b * DIMC + n) * LLEN + l) = st;
            }
        }
    }
}

// ---- Chunked scan (unchanged from round 3) ----
__global__ __launch_bounds__(256)
void scan_part1(const float* __restrict__ dt_t, const float* __restrict__ x_t,
                const float* __restrict__ Bm, const float* __restrict__ A_log,
                float* __restrict__ Pc, float* __restrict__ Qc)
{
    const int tid = threadIdx.x;
    const int n   = tid & 15;
    const int g   = blockIdx.x * 16 + (tid >> 4);
    const int bd  = g >> 6;
    const int chk = g & (NCH - 1);
    const int b   = bd / DIMC;
    const int d   = bd - b * DIMC;

    const float Aval = -__expf(A_log[d * DST + n]);
    const float* dtp = dt_t + (size_t)bd * LLEN + chk * CL;
    const float* xp  = x_t  + (size_t)bd * LLEN + chk * CL;
    const float* Bp  = Bm + ((size_t)b * LLEN + chk * CL) * DST + n;

    float P = 1.f, q = 0.f;
    for (int t0 = 0; t0 < CL; t0 += 4) {
        float4 dt4 = *(const float4*)(dtp + t0);
        float4 x4  = *(const float4*)(xp + t0);
        float bv[4];
        #pragma unroll
        for (int j = 0; j < 4; ++j) bv[j] = Bp[(size_t)(t0 + j) * DST];
        float dts[4] = {dt4.x, dt4.y, dt4.z, dt4.w};
        float xs[4]  = {x4.x, x4.y, x4.z, x4.w};
        #pragma unroll
        for (int j = 0; j < 4; ++j) {
            float a = __expf(dts[j] * Aval);
            P *= a;
            q = fmaf(a, q, dts[j] * xs[j] * bv[j]);
        }
    }
    Pc[(size_t)g * DST + n] = P;
    Qc[(size_t)g * DST + n] = q;
}

__global__ __launch_bounds__(256)
void scan_carry(const float* __restrict__ Pc, const float* __restrict__ Qc,
                float* __restrict__ Hin)
{
    const int idx = blockIdx.x * 256 + threadIdx.x;
    const int bd  = idx >> 4;
    const int n   = idx & 15;
    float h = 0.f;
    for (int chk = 0; chk < NCH; ++chk) {
        size_t o = ((size_t)bd * NCH + chk) * DST + n;
        Hin[o] = h;
        h = fmaf(Pc[o], h, Qc[o]);
    }
}

__global__ __launch_bounds__(256)
void scan_part3(const float* __restrict__ dt_t, const float* __restrict__ x_t,
                const float* __restrict__ Bm, const float* __restrict__ Cm,
                const float* __restrict__ A_log, const float* __restrict__ Dv,
                const float* __restrict__ Hin, float* __restrict__ y_t)
{
    const int tid = threadIdx.x;
    const int n   = tid & 15;
    const int g   = blockIdx.x * 16 + (tid >> 4);
    const int bd  = g >> 6;
    const int chk = g & (NCH - 1);
    const int b   = bd / DIMC;
    const int d   = bd - b * DIMC;

    const float Aval = -__expf(A_log[d * DST + n]);
    const float Dd   = Dv[d];
    const float* dtp = dt_t + (size_t)bd * LLEN + chk * CL;
    const float* xp  = x_t  + (size_t)bd * LLEN + chk * CL;
    const float* Bp  = Bm + ((size_t)b * LLEN + chk * CL) * DST + n;
    const float* Cp  = Cm + ((size_t)b * LLEN + chk * CL) * DST + n;
    float*       yp  = y_t + (size_t)bd * LLEN + chk * CL;

    float h = Hin[(size_t)g * DST + n];
    for (int t0 = 0; t0 < CL; t0 += 4) {
        float4 dt4 = *(const float4*)(dtp + t0);
        float4 x4  = *(const float4*)(xp + t0);
        float bv[4], cv[4];
        #pragma unroll
        for (int j = 0; j < 4; ++j) {
            bv[j] = Bp[(size_t)(t0 + j) * DST];
            cv[j] = Cp[(size_t)(t0 + j) * DST];
        }
        float dts[4] = {dt4.x, dt4.y, dt4.z, dt4.w};
        float xs[4]  = {x4.x, x4.y, x4.z, x4.w};
        float ys[4];
        #pragma unroll
        for (int j = 0; j < 4; ++j) {
            float a = __expf(dts[j] * Aval);
            h = fmaf(a, h, dts[j] * xs[j] * bv[j]);
            float p = h * cv[j];
            p += __shfl_xor(p, 1);
            p += __shfl_xor(p, 2);
            p += __shfl_xor(p, 4);
            p += __shfl_xor(p, 8);
            ys[j] = fmaf(xs[j], Dd, p);
        }
        if (n == 0) {
            float4 st; st.x = ys[0]; st.y = ys[1]; st.z = ys[2]; st.w = ys[3];
            *(float4*)(yp + t0) = st;
        }
    }
}

extern "C" void kernel_launch(void* const* d_in, const int* in_sizes, int n_in,
                              void* d_out, int out_size, void* d_ws, size_t ws_size,
                              hipStream_t stream)
{
    const float* x      = (const float*)d_in[0];
    const float* W_proj = (const float*)d_in[1];
    const float* b_proj = (const float*)d_in[2];
    const float* A_log  = (const float*)d_in[3];
    const float* Dv     = (const float*)d_in[4];
    const float* dt_b   = (const float*)d_in[5];
    const float* W_out  = (const float*)d_in[6];
    const float* b_out  = (const float*)d_in[7];
    float* out = (float*)d_out;
    float* ws  = (float*)d_ws;

    const size_t szBD = (size_t)NB * DIMC * LLEN;        // 6,291,456
    const size_t szBC = (size_t)NB * LLEN * DST;         //   262,144
    const size_t szPQ = (size_t)NB * DIMC * NCH * DST;   // 1,572,864
    float* x_t  = ws;
    float* dt_t = x_t + szBD;
    float* Bmw  = dt_t + szBD;
    float* Cmw  = Bmw + szBC;
    float* y_t  = Cmw + szBC;
    float* Pc   = y_t + szBD;
    float* Qc   = Pc + szPQ;
    float* Hin  = Qc + szPQ;
    ushort* x_bfT = (ushort*)(Hin + szPQ);               // [B][L][K] bf16
    ushort* y_bfT = x_bfT + szBD;                        // [B][L][K] bf16
    ushort* Wp_bf = y_bfT + szBD;                        // [832][384] bf16 (pad)
    ushort* Wo_bf = Wp_bf + (size_t)832 * KDIM;          // [384][384] bf16
    // total ~122.6 MB

    // weight casts (pad W_proj rows to 832 with zeros)
    cast_bf<<<(832 * KDIM) / 1024, 256, 0, stream>>>(W_proj, Wp_bf,
                                                     PDIM * KDIM, 832 * KDIM);
    cast_bf<<<(DIMC * KDIM) / 1024, 256, 0, stream>>>(W_out, Wo_bf,
                                                      DIMC * KDIM, DIMC * KDIM);
    // x: [B][C][L] fp32 -> [B][L][C] bf16
    dim3 tg(LLEN / 64, DIMC / 64, NB);
    transpose_cast<<<tg, 256, 0, stream>>>(x, x_bfT);

    dim3 g1((NB * LLEN) / 128, (PDIM + 63) / 64);
    mfma_gemm<0><<<g1, 256, 0, stream>>>(x_bfT, Wp_bf, b_proj, dt_b,
                                         x_t, dt_t, Bmw, Cmw, nullptr);

    const int ngroups = NB * DIMC * NCH;
    scan_part1<<<ngroups / 16, 256, 0, stream>>>(dt_t, x_t, Bmw, A_log, Pc, Qc);
    scan_carry<<<(NB * DIMC * DST) / 256, 256, 0, stream>>>(Pc, Qc, Hin);
    scan_part3<<<ngroups / 16, 256, 0, stream>>>(dt_t, x_t, Bmw, Cmw,
                                                 A_log, Dv, Hin, y_t);

    // y: [B][D][L] fp32 -> [B][L][D] bf16
    transpose_cast<<<tg, 256, 0, stream>>>(y_t, y_bfT);

    dim3 g2((NB * LLEN) / 128, DIMC / 64);
    mfma_gemm<1><<<g2, 256, 0, stream>>>(y_bfT, Wo_bf, b_out, nullptr,
                                         nullptr, nullptr, nullptr, nullptr,
                                         out);
}

// Round 5
// 245.556 us; speedup vs baseline: 3.2199x; 1.0128x over previous
//
#include <hip/hip_runtime.h>
#include <cstdint>
#include <cstddef>

#define DIMC 384
#define DST  16
#define LLEN 4096
#define NB   4
#define PDIM 800   // 2*DIMC + 2*DST
#define NCH  128
#define CL   32
#define KDIM 384

typedef __attribute__((ext_vector_type(8))) short bf16x8;
typedef __attribute__((ext_vector_type(4))) float f32x4;

#define GLOAD16(g, l) __builtin_amdgcn_global_load_lds( \
    (const __attribute__((address_space(1))) uint32_t*)(g), \
    (__attribute__((address_space(3))) uint32_t*)(l), 16, 0, 0)

__device__ __forceinline__ float softplus_f(float v) {
    if (v > 20.f) return v;
    return logf(1.f + __expf(v));
}

__device__ __forceinline__ ushort f2bf(float x) {
    uint32_t u = __float_as_uint(x);
    uint32_t r = (u + 0x7FFFu + ((u >> 16) & 1u)) >> 16;
    return (ushort)r;
}

// fp32 -> bf16 elementwise; i in [n_src, n_tot) writes zeros (pad rows).
__global__ __launch_bounds__(256)
void cast_bf(const float* __restrict__ in, ushort* __restrict__ out,
             int n_src, int n_tot)
{
    int i = (blockIdx.x * 256 + threadIdx.x) * 4;
    if (i >= n_tot) return;
    if (i < n_src) {
        float4 v = *(const float4*)(in + i);
        ushort4 s; s.x = f2bf(v.x); s.y = f2bf(v.y); s.z = f2bf(v.z); s.w = f2bf(v.w);
        *(ushort4*)(out + i) = s;
    } else {
        ushort4 s; s.x = 0; s.y = 0; s.z = 0; s.w = 0;
        *(ushort4*)(out + i) = s;
    }
}

// in: [B][R=384][C=4096] fp32 ; out: [B][C][R] bf16. 64x64 LDS tile.
__global__ __launch_bounds__(256)
void transpose_cast(const float* __restrict__ in, ushort* __restrict__ out)
{
    __shared__ float t[64][65];
    const int tid = threadIdx.x;
    const int b  = blockIdx.z;
    const int c0 = blockIdx.y * 64;
    const int l0 = blockIdx.x * 64;
    const float* ip = in + ((size_t)b * DIMC + c0) * LLEN + l0;
    #pragma unroll
    for (int r = 0; r < 4; ++r) {
        int cl = (tid >> 4) + r * 16;
        int l4 = (tid & 15) * 4;
        float4 v = *(const float4*)(ip + (size_t)cl * LLEN + l4);
        t[cl][l4 + 0] = v.x; t[cl][l4 + 1] = v.y;
        t[cl][l4 + 2] = v.z; t[cl][l4 + 3] = v.w;
    }
    __syncthreads();
    ushort* op = out + ((size_t)b * LLEN + l0) * DIMC + c0;
    #pragma unroll
    for (int r = 0; r < 4; ++r) {
        int ll = (tid >> 4) + r * 16;
        int c4 = (tid & 15) * 4;
        ushort4 s;
        s.x = f2bf(t[c4 + 0][ll]); s.y = f2bf(t[c4 + 1][ll]);
        s.z = f2bf(t[c4 + 2][ll]); s.w = f2bf(t[c4 + 3][ll]);
        *(ushort4*)(op + (size_t)ll * DIMC + c4) = s;
    }
}

// bf16 MFMA GEMM (unchanged from round 4). Tile 128(m) x 64(n), BK=32, 4 waves.
template<int EPI>
__global__ __launch_bounds__(256)
void mfma_gemm(const ushort* __restrict__ Abf, const ushort* __restrict__ Wbf,
               const float* __restrict__ bias, const float* __restrict__ dt_bias,
               float* __restrict__ o_x, float* __restrict__ o_dt,
               float* __restrict__ o_Bm, float* __restrict__ o_Cm,
               float* __restrict__ o_out)
{
    __shared__ ushort Alds[128 * 32];
    __shared__ ushort Blds[64 * 32];

    const int tid = threadIdx.x;
    const int m0  = blockIdx.x * 128;
    const int n0  = blockIdx.y * 64;
    const int w   = tid >> 6;
    const int ln  = tid & 63;
    const int wm  = w * 32;
    const int fr  = ln & 15;
    const int fg  = ln >> 4;

    const int srow = tid >> 2;
    const int sg   = tid & 3;

    const ushort* Ag = Abf + (size_t)m0 * KDIM;
    const ushort* Bg = Wbf + (size_t)n0 * KDIM;

    f32x4 acc[2][4];
    #pragma unroll
    for (int i = 0; i < 2; ++i)
        #pragma unroll
        for (int j = 0; j < 4; ++j)
            acc[i][j] = (f32x4){0.f, 0.f, 0.f, 0.f};

    for (int k0 = 0; k0 < KDIM; k0 += 32) {
        if (k0) __syncthreads();
        {
            int a0 = sg ^ ((srow >> 1) & 3);
            GLOAD16(Ag + (size_t)srow * KDIM + k0 + a0 * 8, &Alds[tid * 8]);
            int r1 = srow + 64;
            int a1 = sg ^ ((r1 >> 1) & 3);
            GLOAD16(Ag + (size_t)r1 * KDIM + k0 + a1 * 8, &Alds[2048 + tid * 8]);
            GLOAD16(Bg + (size_t)srow * KDIM + k0 + a0 * 8, &Blds[tid * 8]);
        }
        __syncthreads();
        bf16x8 af[2], bfv[4];
        #pragma unroll
        for (int i = 0; i < 2; ++i) {
            int r = wm + i * 16 + fr;
            af[i] = *(const bf16x8*)&Alds[r * 32 + ((fg ^ ((r >> 1) & 3)) << 3)];
        }
        #pragma unroll
        for (int j = 0; j < 4; ++j) {
            int r = j * 16 + fr;
            bfv[j] = *(const bf16x8*)&Blds[r * 32 + ((fg ^ ((r >> 1) & 3)) << 3)];
        }
        #pragma unroll
        for (int i = 0; i < 2; ++i)
            #pragma unroll
            for (int j = 0; j < 4; ++j)
                acc[i][j] = __builtin_amdgcn_mfma_f32_16x16x32_bf16(af[i], bfv[j], acc[i][j], 0, 0, 0);
    }

    const int b   = m0 / LLEN;
    const int ml0 = m0 - b * LLEN;
    #pragma unroll
    for (int j = 0; j < 4; ++j) {
        const int n = n0 + j * 16 + fr;
        #pragma unroll
        for (int i = 0; i < 2; ++i) {
            const int l = ml0 + wm + i * 16 + fg * 4;
            f32x4 v = acc[i][j];
            if (EPI == 0) {
                if (n < DIMC) {
                    const float bb = bias[n];
                    float4 st; st.x = v[0] + bb; st.y = v[1] + bb; st.z = v[2] + bb; st.w = v[3] + bb;
                    *(float4*)(o_x + ((size_t)b * DIMC + n) * LLEN + l) = st;
                } else if (n < 2 * DIMC) {
                    const int d = n - DIMC;
                    const float bb = bias[n] + dt_bias[d];
                    float4 st;
                    st.x = softplus_f(v[0] + bb); st.y = softplus_f(v[1] + bb);
                    st.z = softplus_f(v[2] + bb); st.w = softplus_f(v[3] + bb);
                    *(float4*)(o_dt + ((size_t)b * DIMC + d) * LLEN + l) = st;
                } else if (n < 2 * DIMC + DST) {
                    const int s = n - 2 * DIMC;
                    const float bb = bias[n];
                    #pragma unroll
                    for (int r = 0; r < 4; ++r)
                        o_Bm[((size_t)b * LLEN + l + r) * DST + s] = v[r] + bb;
                } else if (n < PDIM) {
                    const int s = n - 2 * DIMC - DST;
                    const float bb = bias[n];
                    #pragma unroll
                    for (int r = 0; r < 4; ++r)
                        o_Cm[((size_t)b * LLEN + l + r) * DST + s] = v[r] + bb;
                }
            } else {
                const float bb = bias[n];
                float4 st; st.x = v[0] + bb; st.y = v[1] + bb; st.z = v[2] + bb; st.w = v[3] + bb;
                *(float4*)(o_out + ((size_t)b * DIMC + n) * LLEN + l) = st;
            }
        }
    }
}

// ---- Chunked scan, thread-owns-16-states version ----
// Block = 384 threads (= all d) for one (b, chunk). B staged in LDS.
// Pc/Qc/Hin layout: [b][chk][d][16].
__global__ __launch_bounds__(384)
void scan_part1(const float* __restrict__ dt_t, const float* __restrict__ x_t,
                const float* __restrict__ Bm, const float* __restrict__ A_log,
                float* __restrict__ Pc, float* __restrict__ Qc)
{
    __shared__ float Bs[CL][DST];
    const int d   = threadIdx.x;
    const int b   = blockIdx.x >> 7;          // NCH = 128
    const int chk = blockIdx.x & (NCH - 1);
    const int l0  = chk * CL;

    if (d < (CL * DST) / 4)
        ((float4*)&Bs[0][0])[d] =
            ((const float4*)(Bm + ((size_t)b * LLEN + l0) * DST))[d];

    float Av[DST];
    #pragma unroll
    for (int r = 0; r < 4; ++r) {
        float4 v = *(const float4*)(A_log + d * DST + r * 4);
        Av[r*4+0] = -__expf(v.x); Av[r*4+1] = -__expf(v.y);
        Av[r*4+2] = -__expf(v.z); Av[r*4+3] = -__expf(v.w);
    }
    __syncthreads();

    const float* dtp = dt_t + ((size_t)b * DIMC + d) * LLEN + l0;
    const float* xp  = x_t  + ((size_t)b * DIMC + d) * LLEN + l0;

    float P[DST], q[DST];
    #pragma unroll
    for (int n = 0; n < DST; ++n) { P[n] = 1.f; q[n] = 0.f; }

    for (int t0 = 0; t0 < CL; t0 += 4) {
        float4 dt4 = *(const float4*)(dtp + t0);
        float4 x4  = *(const float4*)(xp + t0);
        float dts[4] = {dt4.x, dt4.y, dt4.z, dt4.w};
        float xs[4]  = {x4.x, x4.y, x4.z, x4.w};
        #pragma unroll
        for (int j = 0; j < 4; ++j) {
            const float dt  = dts[j];
            const float dtx = dt * xs[j];
            #pragma unroll
            for (int n = 0; n < DST; ++n) {
                float a = __expf(dt * Av[n]);
                P[n] *= a;
                q[n] = fmaf(a, q[n], dtx * Bs[t0 + j][n]);
            }
        }
    }
    const size_t o = (((size_t)b * NCH + chk) * DIMC + d) * DST;
    #pragma unroll
    for (int r = 0; r < 4; ++r) {
        *(float4*)(Pc + o + r * 4) = *(float4*)&P[r * 4];
        *(float4*)(Qc + o + r * 4) = *(float4*)&q[r * 4];
    }
}

__global__ __launch_bounds__(256)
void scan_carry(const float* __restrict__ Pc, const float* __restrict__ Qc,
                float* __restrict__ Hin)
{
    const int idx = blockIdx.x * 256 + threadIdx.x;   // over B*DIMC*16
    const int bd  = idx >> 4;
    const int n   = idx & 15;
    const int b   = bd / DIMC;
    const int d   = bd - b * DIMC;
    float h = 0.f;
    for (int chk = 0; chk < NCH; ++chk) {
        const size_t o = (((size_t)b * NCH + chk) * DIMC + d) * DST + n;
        Hin[o] = h;
        h = fmaf(Pc[o], h, Qc[o]);
    }
}

// Pass 3: local rescan from Hin; y written directly as bf16 transposed [b][l][d].
__global__ __launch_bounds__(384)
void scan_part3(const float* __restrict__ dt_t, const float* __restrict__ x_t,
                const float* __restrict__ Bm, const float* __restrict__ Cm,
                const float* __restrict__ A_log, const float* __restrict__ Dv,
                const float* __restrict__ Hin, ushort* __restrict__ y_bfT)
{
    __shared__ float Bs[CL][DST];
    __shared__ float Cs[CL][DST];
    const int d   = threadIdx.x;
    const int b   = blockIdx.x >> 7;
    const int chk = blockIdx.x & (NCH - 1);
    const int l0  = chk * CL;

    if (d < 128)
        ((float4*)&Bs[0][0])[d] =
            ((const float4*)(Bm + ((size_t)b * LLEN + l0) * DST))[d];
    else if (d < 256)
        ((float4*)&Cs[0][0])[d - 128] =
            ((const float4*)(Cm + ((size_t)b * LLEN + l0) * DST))[d - 128];

    float Av[DST];
    #pragma unroll
    for (int r = 0; r < 4; ++r) {
        float4 v = *(const float4*)(A_log + d * DST + r * 4);
        Av[r*4+0] = -__expf(v.x); Av[r*4+1] = -__expf(v.y);
        Av[r*4+2] = -__expf(v.z); Av[r*4+3] = -__expf(v.w);
    }
    const float Dd = Dv[d];
    __syncthreads();

    float h[DST];
    const size_t ho = (((size_t)b * NCH + chk) * DIMC + d) * DST;
    #pragma unroll
    for (int r = 0; r < 4; ++r)
        *(float4*)&h[r * 4] = *(const float4*)(Hin + ho + r * 4);

    const float* dtp = dt_t + ((size_t)b * DIMC + d) * LLEN + l0;
    const float* xp  = x_t  + ((size_t)b * DIMC + d) * LLEN + l0;
    ushort* yp = y_bfT + ((size_t)b * LLEN + l0) * DIMC + d;

    for (int t0 = 0; t0 < CL; t0 += 4) {
        float4 dt4 = *(const float4*)(dtp + t0);
        float4 x4  = *(const float4*)(xp + t0);
        float dts[4] = {dt4.x, dt4.y, dt4.z, dt4.w};
        float xs[4]  = {x4.x, x4.y, x4.z, x4.w};
        #pragma unroll
        for (int j = 0; j < 4; ++j) {
            const float dt  = dts[j];
            const float xx  = xs[j];
            const float dtx = dt * xx;
            float yv = Dd * xx;
            #pragma unroll
            for (int n = 0; n < DST; ++n) {
                float a = __expf(dt * Av[n]);
                h[n] = fmaf(a, h[n], dtx * Bs[t0 + j][n]);
                yv = fmaf(h[n], Cs[t0 + j][n], yv);
            }
            yp[(size_t)(t0 + j) * DIMC] = f2bf(yv);
        }
    }
}

extern "C" void kernel_launch(void* const* d_in, const int* in_sizes, int n_in,
                              void* d_out, int out_size, void* d_ws, size_t ws_size,
                              hipStream_t stream)
{
    const float* x      = (const float*)d_in[0];
    const float* W_proj = (const float*)d_in[1];
    const float* b_proj = (const float*)d_in[2];
    const float* A_log  = (const float*)d_in[3];
    const float* Dv     = (const float*)d_in[4];
    const float* dt_b   = (const float*)d_in[5];
    const float* W_out  = (const float*)d_in[6];
    const float* b_out  = (const float*)d_in[7];
    float* out = (float*)d_out;
    float* ws  = (float*)d_ws;

    const size_t szBD = (size_t)NB * DIMC * LLEN;          // 6,291,456
    const size_t szBC = (size_t)NB * LLEN * DST;           //   262,144
    const size_t szPQ = (size_t)NB * NCH * DIMC * DST;     // 3,145,728
    float* x_t  = ws;
    float* dt_t = x_t + szBD;
    float* Bmw  = dt_t + szBD;
    float* Cmw  = Bmw + szBC;
    float* Pc   = Cmw + szBC;
    float* Qc   = Pc + szPQ;
    float* Hin  = Qc + szPQ;
    ushort* x_bfT = (ushort*)(Hin + szPQ);                 // [B][L][K] bf16
    ushort* y_bfT = x_bfT + szBD;                          // [B][L][K] bf16
    ushort* Wp_bf = y_bfT + szBD;                          // [832][384] bf16
    ushort* Wo_bf = Wp_bf + (size_t)832 * KDIM;            // [384][384] bf16
    // total ~116 MB

    cast_bf<<<(832 * KDIM) / 1024, 256, 0, stream>>>(W_proj, Wp_bf,
                                                     PDIM * KDIM, 832 * KDIM);
    cast_bf<<<(DIMC * KDIM) / 1024, 256, 0, stream>>>(W_out, Wo_bf,
                                                      DIMC * KDIM, DIMC * KDIM);
    dim3 tg(LLEN / 64, DIMC / 64, NB);
    transpose_cast<<<tg, 256, 0, stream>>>(x, x_bfT);

    dim3 g1((NB * LLEN) / 128, (PDIM + 63) / 64);
    mfma_gemm<0><<<g1, 256, 0, stream>>>(x_bfT, Wp_bf, b_proj, dt_b,
                                         x_t, dt_t, Bmw, Cmw, nullptr);

    scan_part1<<<NB * NCH, 384, 0, stream>>>(dt_t, x_t, Bmw, A_log, Pc, Qc);
    scan_carry<<<(NB * DIMC * DST) / 256, 256, 0, stream>>>(Pc, Qc, Hin);
    scan_part3<<<NB * NCH, 384, 0, stream>>>(dt_t, x_t, Bmw, Cmw,
                                             A_log, Dv, Hin, y_bfT);

    dim3 g2((NB * LLEN) / 128, DIMC / 64);
    mfma_gemm<1><<<g2, 256, 0, stream>>>(y_bfT, Wo_bf, b_out, nullptr,
                                         nullptr, nullptr, nullptr, nullptr,
                                         out);
}

// Round 6
// 210.344 us; speedup vs baseline: 3.7589x; 1.1674x over previous
//
#include <hip/hip_runtime.h>
#include <cstdint>
#include <cstddef>

#define DIMC 384
#define DST  16
#define LLEN 4096
#define NB   4
#define PDIM 800   // 2*DIMC + 2*DST
#define NCH  128
#define CL   32
#define KDIM 384

typedef __attribute__((ext_vector_type(8))) short bf16x8;
typedef __attribute__((ext_vector_type(4))) float f32x4;

#define GLOAD16(g, l) __builtin_amdgcn_global_load_lds( \
    (const __attribute__((address_space(1))) uint32_t*)(g), \
    (__attribute__((address_space(3))) uint32_t*)(l), 16, 0, 0)

__device__ __forceinline__ float softplus_f(float v) {
    if (v > 20.f) return v;
    return logf(1.f + __expf(v));
}

__device__ __forceinline__ ushort f2bf(float x) {
    uint32_t u = __float_as_uint(x);
    uint32_t r = (u + 0x7FFFu + ((u >> 16) & 1u)) >> 16;
    return (ushort)r;
}

// fp32 -> bf16 elementwise; i in [n_src, n_tot) writes zeros (pad rows).
__global__ __launch_bounds__(256)
void cast_bf(const float* __restrict__ in, ushort* __restrict__ out,
             int n_src, int n_tot)
{
    int i = (blockIdx.x * 256 + threadIdx.x) * 4;
    if (i >= n_tot) return;
    if (i < n_src) {
        float4 v = *(const float4*)(in + i);
        ushort4 s; s.x = f2bf(v.x); s.y = f2bf(v.y); s.z = f2bf(v.z); s.w = f2bf(v.w);
        *(ushort4*)(out + i) = s;
    } else {
        ushort4 s; s.x = 0; s.y = 0; s.z = 0; s.w = 0;
        *(ushort4*)(out + i) = s;
    }
}

// in: [B][R=384][C=4096] fp32 ; out: [B][C][R] bf16. 64x64 LDS tile.
__global__ __launch_bounds__(256)
void transpose_cast(const float* __restrict__ in, ushort* __restrict__ out)
{
    __shared__ float t[64][65];
    const int tid = threadIdx.x;
    const int b  = blockIdx.z;
    const int c0 = blockIdx.y * 64;
    const int l0 = blockIdx.x * 64;
    const float* ip = in + ((size_t)b * DIMC + c0) * LLEN + l0;
    #pragma unroll
    for (int r = 0; r < 4; ++r) {
        int cl = (tid >> 4) + r * 16;
        int l4 = (tid & 15) * 4;
        float4 v = *(const float4*)(ip + (size_t)cl * LLEN + l4);
        t[cl][l4 + 0] = v.x; t[cl][l4 + 1] = v.y;
        t[cl][l4 + 2] = v.z; t[cl][l4 + 3] = v.w;
    }
    __syncthreads();
    ushort* op = out + ((size_t)b * LLEN + l0) * DIMC + c0;
    #pragma unroll
    for (int r = 0; r < 4; ++r) {
        int ll = (tid >> 4) + r * 16;
        int c4 = (tid & 15) * 4;
        ushort4 s;
        s.x = f2bf(t[c4 + 0][ll]); s.y = f2bf(t[c4 + 1][ll]);
        s.z = f2bf(t[c4 + 2][ll]); s.w = f2bf(t[c4 + 3][ll]);
        *(ushort4*)(op + (size_t)ll * DIMC + c4) = s;
    }
}

// bf16 MFMA GEMM. Tile 128(m) x 64(n), BK=32, 4 waves.
// EPI 0: proj epilogue — x_in/delta stored TIME-MAJOR [b][l][d] fp32.
// EPI 1: out epilogue (store [b][n][l] fp32 + bias).
template<int EPI>
__global__ __launch_bounds__(256)
void mfma_gemm(const ushort* __restrict__ Abf, const ushort* __restrict__ Wbf,
               const float* __restrict__ bias, const float* __restrict__ dt_bias,
               float* __restrict__ o_x, float* __restrict__ o_dt,
               float* __restrict__ o_Bm, float* __restrict__ o_Cm,
               float* __restrict__ o_out)
{
    __shared__ ushort Alds[128 * 32];
    __shared__ ushort Blds[64 * 32];

    const int tid = threadIdx.x;
    const int m0  = blockIdx.x * 128;
    const int n0  = blockIdx.y * 64;
    const int w   = tid >> 6;
    const int ln  = tid & 63;
    const int wm  = w * 32;
    const int fr  = ln & 15;
    const int fg  = ln >> 4;

    const int srow = tid >> 2;
    const int sg   = tid & 3;

    const ushort* Ag = Abf + (size_t)m0 * KDIM;
    const ushort* Bg = Wbf + (size_t)n0 * KDIM;

    f32x4 acc[2][4];
    #pragma unroll
    for (int i = 0; i < 2; ++i)
        #pragma unroll
        for (int j = 0; j < 4; ++j)
            acc[i][j] = (f32x4){0.f, 0.f, 0.f, 0.f};

    for (int k0 = 0; k0 < KDIM; k0 += 32) {
        if (k0) __syncthreads();
        {
            int a0 = sg ^ ((srow >> 1) & 3);
            GLOAD16(Ag + (size_t)srow * KDIM + k0 + a0 * 8, &Alds[tid * 8]);
            int r1 = srow + 64;
            int a1 = sg ^ ((r1 >> 1) & 3);
            GLOAD16(Ag + (size_t)r1 * KDIM + k0 + a1 * 8, &Alds[2048 + tid * 8]);
            GLOAD16(Bg + (size_t)srow * KDIM + k0 + a0 * 8, &Blds[tid * 8]);
        }
        __syncthreads();
        bf16x8 af[2], bfv[4];
        #pragma unroll
        for (int i = 0; i < 2; ++i) {
            int r = wm + i * 16 + fr;
            af[i] = *(const bf16x8*)&Alds[r * 32 + ((fg ^ ((r >> 1) & 3)) << 3)];
        }
        #pragma unroll
        for (int j = 0; j < 4; ++j) {
            int r = j * 16 + fr;
            bfv[j] = *(const bf16x8*)&Blds[r * 32 + ((fg ^ ((r >> 1) & 3)) << 3)];
        }
        #pragma unroll
        for (int i = 0; i < 2; ++i)
            #pragma unroll
            for (int j = 0; j < 4; ++j)
                acc[i][j] = __builtin_amdgcn_mfma_f32_16x16x32_bf16(af[i], bfv[j], acc[i][j], 0, 0, 0);
    }

    const int b   = m0 / LLEN;
    const int ml0 = m0 - b * LLEN;
    #pragma unroll
    for (int j = 0; j < 4; ++j) {
        const int n = n0 + j * 16 + fr;
        #pragma unroll
        for (int i = 0; i < 2; ++i) {
            const int l = ml0 + wm + i * 16 + fg * 4;
            f32x4 v = acc[i][j];
            if (EPI == 0) {
                if (n < DIMC) {
                    const float bb = bias[n];
                    #pragma unroll
                    for (int r = 0; r < 4; ++r)
                        o_x[((size_t)b * LLEN + l + r) * DIMC + n] = v[r] + bb;
                } else if (n < 2 * DIMC) {
                    const int d = n - DIMC;
                    const float bb = bias[n] + dt_bias[d];
                    #pragma unroll
                    for (int r = 0; r < 4; ++r)
                        o_dt[((size_t)b * LLEN + l + r) * DIMC + d] = softplus_f(v[r] + bb);
                } else if (n < 2 * DIMC + DST) {
                    const int s = n - 2 * DIMC;
                    const float bb = bias[n];
                    #pragma unroll
                    for (int r = 0; r < 4; ++r)
                        o_Bm[((size_t)b * LLEN + l + r) * DST + s] = v[r] + bb;
                } else if (n < PDIM) {
                    const int s = n - 2 * DIMC - DST;
                    const float bb = bias[n];
                    #pragma unroll
                    for (int r = 0; r < 4; ++r)
                        o_Cm[((size_t)b * LLEN + l + r) * DST + s] = v[r] + bb;
                }
            } else {
                const float bb = bias[n];
                float4 st; st.x = v[0] + bb; st.y = v[1] + bb; st.z = v[2] + bb; st.w = v[3] + bb;
                *(float4*)(o_out + ((size_t)b * DIMC + n) * LLEN + l) = st;
            }
        }
    }
}

// ---- Chunked scan, time-major dt/x ([b][l][d] fp32) ----
// Block = 384 threads (= all d) for one (b, chunk). B (and C) staged in LDS.
// Pc/Qc/Hin layout: [b][chk][d][16].
__global__ __launch_bounds__(384)
void scan_part1(const float* __restrict__ dt_t, const float* __restrict__ x_t,
                const float* __restrict__ Bm, const float* __restrict__ A_log,
                float* __restrict__ Pc, float* __restrict__ Qc)
{
    __shared__ float Bs[CL][DST];
    const int d   = threadIdx.x;
    const int b   = blockIdx.x >> 7;          // NCH = 128
    const int chk = blockIdx.x & (NCH - 1);
    const int l0  = chk * CL;

    if (d < (CL * DST) / 4)
        ((float4*)&Bs[0][0])[d] =
            ((const float4*)(Bm + ((size_t)b * LLEN + l0) * DST))[d];

    float Av[DST];
    #pragma unroll
    for (int r = 0; r < 4; ++r) {
        float4 v = *(const float4*)(A_log + d * DST + r * 4);
        Av[r*4+0] = -__expf(v.x); Av[r*4+1] = -__expf(v.y);
        Av[r*4+2] = -__expf(v.z); Av[r*4+3] = -__expf(v.w);
    }
    __syncthreads();

    const float* dtp = dt_t + ((size_t)b * LLEN + l0) * DIMC + d;
    const float* xp  = x_t  + ((size_t)b * LLEN + l0) * DIMC + d;

    float P[DST], q[DST];
    #pragma unroll
    for (int n = 0; n < DST; ++n) { P[n] = 1.f; q[n] = 0.f; }

    for (int t0 = 0; t0 < CL; t0 += 4) {
        float dts[4], xs[4];
        #pragma unroll
        for (int j = 0; j < 4; ++j) {
            dts[j] = dtp[(size_t)(t0 + j) * DIMC];
            xs[j]  = xp[(size_t)(t0 + j) * DIMC];
        }
        #pragma unroll
        for (int j = 0; j < 4; ++j) {
            const float dt  = dts[j];
            const float dtx = dt * xs[j];
            #pragma unroll
            for (int n = 0; n < DST; ++n) {
                float a = __expf(dt * Av[n]);
                P[n] *= a;
                q[n] = fmaf(a, q[n], dtx * Bs[t0 + j][n]);
            }
        }
    }
    const size_t o = (((size_t)b * NCH + chk) * DIMC + d) * DST;
    #pragma unroll
    for (int r = 0; r < 4; ++r) {
        *(float4*)(Pc + o + r * 4) = *(float4*)&P[r * 4];
        *(float4*)(Qc + o + r * 4) = *(float4*)&q[r * 4];
    }
}

__global__ __launch_bounds__(256)
void scan_carry(const float* __restrict__ Pc, const float* __restrict__ Qc,
                float* __restrict__ Hin)
{
    const int idx = blockIdx.x * 256 + threadIdx.x;   // over B*DIMC*16
    const int bd  = idx >> 4;
    const int n   = idx & 15;
    const int b   = bd / DIMC;
    const int d   = bd - b * DIMC;
    float h = 0.f;
    for (int chk = 0; chk < NCH; ++chk) {
        const size_t o = (((size_t)b * NCH + chk) * DIMC + d) * DST + n;
        Hin[o] = h;
        h = fmaf(Pc[o], h, Qc[o]);
    }
}

// Pass 3: local rescan from Hin; y written directly as bf16 transposed [b][l][d].
__global__ __launch_bounds__(384)
void scan_part3(const float* __restrict__ dt_t, const float* __restrict__ x_t,
                const float* __restrict__ Bm, const float* __restrict__ Cm,
                const float* __restrict__ A_log, const float* __restrict__ Dv,
                const float* __restrict__ Hin, ushort* __restrict__ y_bfT)
{
    __shared__ float Bs[CL][DST];
    __shared__ float Cs[CL][DST];
    const int d   = threadIdx.x;
    const int b   = blockIdx.x >> 7;
    const int chk = blockIdx.x & (NCH - 1);
    const int l0  = chk * CL;

    if (d < 128)
        ((float4*)&Bs[0][0])[d] =
            ((const float4*)(Bm + ((size_t)b * LLEN + l0) * DST))[d];
    else if (d < 256)
        ((float4*)&Cs[0][0])[d - 128] =
            ((const float4*)(Cm + ((size_t)b * LLEN + l0) * DST))[d - 128];

    float Av[DST];
    #pragma unroll
    for (int r = 0; r < 4; ++r) {
        float4 v = *(const float4*)(A_log + d * DST + r * 4);
        Av[r*4+0] = -__expf(v.x); Av[r*4+1] = -__expf(v.y);
        Av[r*4+2] = -__expf(v.z); Av[r*4+3] = -__expf(v.w);
    }
    const float Dd = Dv[d];
    __syncthreads();

    float h[DST];
    const size_t ho = (((size_t)b * NCH + chk) * DIMC + d) * DST;
    #pragma unroll
    for (int r = 0; r < 4; ++r)
        *(float4*)&h[r * 4] = *(const float4*)(Hin + ho + r * 4);

    const float* dtp = dt_t + ((size_t)b * LLEN + l0) * DIMC + d;
    const float* xp  = x_t  + ((size_t)b * LLEN + l0) * DIMC + d;
    ushort* yp = y_bfT + ((size_t)b * LLEN + l0) * DIMC + d;

    for (int t0 = 0; t0 < CL; t0 += 4) {
        float dts[4], xs[4];
        #pragma unroll
        for (int j = 0; j < 4; ++j) {
            dts[j] = dtp[(size_t)(t0 + j) * DIMC];
            xs[j]  = xp[(size_t)(t0 + j) * DIMC];
        }
        #pragma unroll
        for (int j = 0; j < 4; ++j) {
            const float dt  = dts[j];
            const float xx  = xs[j];
            const float dtx = dt * xx;
            float yv = Dd * xx;
            #pragma unroll
            for (int n = 0; n < DST; ++n) {
                float a = __expf(dt * Av[n]);
                h[n] = fmaf(a, h[n], dtx * Bs[t0 + j][n]);
                yv = fmaf(h[n], Cs[t0 + j][n], yv);
            }
            yp[(size_t)(t0 + j) * DIMC] = f2bf(yv);
        }
    }
}

extern "C" void kernel_launch(void* const* d_in, const int* in_sizes, int n_in,
                              void* d_out, int out_size, void* d_ws, size_t ws_size,
                              hipStream_t stream)
{
    const float* x      = (const float*)d_in[0];
    const float* W_proj = (const float*)d_in[1];
    const float* b_proj = (const float*)d_in[2];
    const float* A_log  = (const float*)d_in[3];
    const float* Dv     = (const float*)d_in[4];
    const float* dt_b   = (const float*)d_in[5];
    const float* W_out  = (const float*)d_in[6];
    const float* b_out  = (const float*)d_in[7];
    float* out = (float*)d_out;
    float* ws  = (float*)d_ws;

    const size_t szBD = (size_t)NB * DIMC * LLEN;          // 6,291,456
    const size_t szBC = (size_t)NB * LLEN * DST;           //   262,144
    const size_t szPQ = (size_t)NB * NCH * DIMC * DST;     // 3,145,728
    float* x_t  = ws;                                      // [B][L][D] fp32
    float* dt_t = x_t + szBD;                              // [B][L][D] fp32
    float* Bmw  = dt_t + szBD;
    float* Cmw  = Bmw + szBC;
    float* Pc   = Cmw + szBC;
    float* Qc   = Pc + szPQ;
    float* Hin  = Qc + szPQ;
    ushort* x_bfT = (ushort*)(Hin + szPQ);                 // [B][L][K] bf16
    ushort* y_bfT = x_bfT + szBD;                          // [B][L][K] bf16
    ushort* Wp_bf = y_bfT + szBD;                          // [832][384] bf16
    ushort* Wo_bf = Wp_bf + (size_t)832 * KDIM;            // [384][384] bf16

    cast_bf<<<(832 * KDIM) / 1024, 256, 0, stream>>>(W_proj, Wp_bf,
                                                     PDIM * KDIM, 832 * KDIM);
    cast_bf<<<(DIMC * KDIM) / 1024, 256, 0, stream>>>(W_out, Wo_bf,
                                                      DIMC * KDIM, DIMC * KDIM);
    dim3 tg(LLEN / 64, DIMC / 64, NB);
    transpose_cast<<<tg, 256, 0, stream>>>(x, x_bfT);

    dim3 g1((NB * LLEN) / 128, (PDIM + 63) / 64);
    mfma_gemm<0><<<g1, 256, 0, stream>>>(x_bfT, Wp_bf, b_proj, dt_b,
                                         x_t, dt_t, Bmw, Cmw, nullptr);

    scan_part1<<<NB * NCH, 384, 0, stream>>>(dt_t, x_t, Bmw, A_log, Pc, Qc);
    scan_carry<<<(NB * DIMC * DST) / 256, 256, 0, stream>>>(Pc, Qc, Hin);
    scan_part3<<<NB * NCH, 384, 0, stream>>>(dt_t, x_t, Bmw, Cmw,
                                             A_log, Dv, Hin, y_bfT);

    dim3 g2((NB * LLEN) / 128, DIMC / 64);
    mfma_gemm<1><<<g2, 256, 0, stream>>>(y_bfT, Wo_bf, b_out, nullptr,
                                         nullptr, nullptr, nullptr, nullptr,
                                         out);
}

// Round 7
// 202.421 us; speedup vs baseline: 3.9060x; 1.0391x over previous
//
#include <hip/hip_runtime.h>
#include <cstdint>
#include <cstddef>

#define DIMC 384
#define DST  16
#define LLEN 4096
#define NB   4
#define PDIM 800   // 2*DIMC + 2*DST
#define NCH  128
#define CL   32
#define KDIM 384

typedef __attribute__((ext_vector_type(8))) short bf16x8;
typedef __attribute__((ext_vector_type(4))) float f32x4;

#define GLOAD16(g, l) __builtin_amdgcn_global_load_lds( \
    (const __attribute__((address_space(1))) uint32_t*)(g), \
    (__attribute__((address_space(3))) uint32_t*)(l), 16, 0, 0)

__device__ __forceinline__ float softplus_f(float v) {
    if (v > 20.f) return v;
    return logf(1.f + __expf(v));
}

__device__ __forceinline__ ushort f2bf(float x) {
    uint32_t u = __float_as_uint(x);
    uint32_t r = (u + 0x7FFFu + ((u >> 16) & 1u)) >> 16;
    return (ushort)r;
}
__device__ __forceinline__ float bf2f(ushort u) {
    return __uint_as_float(((uint32_t)u) << 16);
}

// Both weight casts in one launch. W_proj padded to 832 rows with zeros.
__global__ __launch_bounds__(256)
void cast_weights(const float* __restrict__ Wp, const float* __restrict__ Wo,
                  ushort* __restrict__ outp, ushort* __restrict__ outo)
{
    const int np = 832 * KDIM;
    const int no = DIMC * KDIM;
    int i = (blockIdx.x * 256 + threadIdx.x) * 4;
    if (i < np) {
        ushort4 s;
        if (i < PDIM * KDIM) {
            float4 v = *(const float4*)(Wp + i);
            s.x = f2bf(v.x); s.y = f2bf(v.y); s.z = f2bf(v.z); s.w = f2bf(v.w);
        } else { s.x = 0; s.y = 0; s.z = 0; s.w = 0; }
        *(ushort4*)(outp + i) = s;
    } else {
        int k = i - np;
        if (k < no) {
            float4 v = *(const float4*)(Wo + k);
            ushort4 s; s.x = f2bf(v.x); s.y = f2bf(v.y); s.z = f2bf(v.z); s.w = f2bf(v.w);
            *(ushort4*)(outo + k) = s;
        }
    }
}

// in: [B][R=384][C=4096] fp32 ; out: [B][C][R] bf16. 64x64 LDS tile.
__global__ __launch_bounds__(256)
void transpose_cast(const float* __restrict__ in, ushort* __restrict__ out)
{
    __shared__ float t[64][65];
    const int tid = threadIdx.x;
    const int b  = blockIdx.z;
    const int c0 = blockIdx.y * 64;
    const int l0 = blockIdx.x * 64;
    const float* ip = in + ((size_t)b * DIMC + c0) * LLEN + l0;
    #pragma unroll
    for (int r = 0; r < 4; ++r) {
        int cl = (tid >> 4) + r * 16;
        int l4 = (tid & 15) * 4;
        float4 v = *(const float4*)(ip + (size_t)cl * LLEN + l4);
        t[cl][l4 + 0] = v.x; t[cl][l4 + 1] = v.y;
        t[cl][l4 + 2] = v.z; t[cl][l4 + 3] = v.w;
    }
    __syncthreads();
    ushort* op = out + ((size_t)b * LLEN + l0) * DIMC + c0;
    #pragma unroll
    for (int r = 0; r < 4; ++r) {
        int ll = (tid >> 4) + r * 16;
        int c4 = (tid & 15) * 4;
        ushort4 s;
        s.x = f2bf(t[c4 + 0][ll]); s.y = f2bf(t[c4 + 1][ll]);
        s.z = f2bf(t[c4 + 2][ll]); s.w = f2bf(t[c4 + 3][ll]);
        *(ushort4*)(op + (size_t)ll * DIMC + c4) = s;
    }
}

// bf16 MFMA GEMM. Tile 128(m) x 64(n), BK=32, 4 waves.
// EPI 0: proj epilogue — x_in/delta stored TIME-MAJOR [b][l][d] bf16.
// EPI 1: out epilogue (store [b][n][l] fp32 + bias).
template<int EPI>
__global__ __launch_bounds__(256)
void mfma_gemm(const ushort* __restrict__ Abf, const ushort* __restrict__ Wbf,
               const float* __restrict__ bias, const float* __restrict__ dt_bias,
               ushort* __restrict__ o_x, ushort* __restrict__ o_dt,
               float* __restrict__ o_Bm, float* __restrict__ o_Cm,
               float* __restrict__ o_out)
{
    __shared__ ushort Alds[128 * 32];
    __shared__ ushort Blds[64 * 32];

    const int tid = threadIdx.x;
    const int m0  = blockIdx.x * 128;
    const int n0  = blockIdx.y * 64;
    const int w   = tid >> 6;
    const int ln  = tid & 63;
    const int wm  = w * 32;
    const int fr  = ln & 15;
    const int fg  = ln >> 4;

    const int srow = tid >> 2;
    const int sg   = tid & 3;

    const ushort* Ag = Abf + (size_t)m0 * KDIM;
    const ushort* Bg = Wbf + (size_t)n0 * KDIM;

    f32x4 acc[2][4];
    #pragma unroll
    for (int i = 0; i < 2; ++i)
        #pragma unroll
        for (int j = 0; j < 4; ++j)
            acc[i][j] = (f32x4){0.f, 0.f, 0.f, 0.f};

    for (int k0 = 0; k0 < KDIM; k0 += 32) {
        if (k0) __syncthreads();
        {
            int a0 = sg ^ ((srow >> 1) & 3);
            GLOAD16(Ag + (size_t)srow * KDIM + k0 + a0 * 8, &Alds[tid * 8]);
            int r1 = srow + 64;
            int a1 = sg ^ ((r1 >> 1) & 3);
            GLOAD16(Ag + (size_t)r1 * KDIM + k0 + a1 * 8, &Alds[2048 + tid * 8]);
            GLOAD16(Bg + (size_t)srow * KDIM + k0 + a0 * 8, &Blds[tid * 8]);
        }
        __syncthreads();
        bf16x8 af[2], bfv[4];
        #pragma unroll
        for (int i = 0; i < 2; ++i) {
            int r = wm + i * 16 + fr;
            af[i] = *(const bf16x8*)&Alds[r * 32 + ((fg ^ ((r >> 1) & 3)) << 3)];
        }
        #pragma unroll
        for (int j = 0; j < 4; ++j) {
            int r = j * 16 + fr;
            bfv[j] = *(const bf16x8*)&Blds[r * 32 + ((fg ^ ((r >> 1) & 3)) << 3)];
        }
        #pragma unroll
        for (int i = 0; i < 2; ++i)
            #pragma unroll
            for (int j = 0; j < 4; ++j)
                acc[i][j] = __builtin_amdgcn_mfma_f32_16x16x32_bf16(af[i], bfv[j], acc[i][j], 0, 0, 0);
    }

    const int b   = m0 / LLEN;
    const int ml0 = m0 - b * LLEN;
    #pragma unroll
    for (int j = 0; j < 4; ++j) {
        const int n = n0 + j * 16 + fr;
        #pragma unroll
        for (int i = 0; i < 2; ++i) {
            const int l = ml0 + wm + i * 16 + fg * 4;
            f32x4 v = acc[i][j];
            if (EPI == 0) {
                if (n < DIMC) {
                    const float bb = bias[n];
                    #pragma unroll
                    for (int r = 0; r < 4; ++r)
                        o_x[((size_t)b * LLEN + l + r) * DIMC + n] = f2bf(v[r] + bb);
                } else if (n < 2 * DIMC) {
                    const int d = n - DIMC;
                    const float bb = bias[n] + dt_bias[d];
                    #pragma unroll
                    for (int r = 0; r < 4; ++r)
                        o_dt[((size_t)b * LLEN + l + r) * DIMC + d] = f2bf(softplus_f(v[r] + bb));
                } else if (n < 2 * DIMC + DST) {
                    const int s = n - 2 * DIMC;
                    const float bb = bias[n];
                    #pragma unroll
                    for (int r = 0; r < 4; ++r)
                        o_Bm[((size_t)b * LLEN + l + r) * DST + s] = v[r] + bb;
                } else if (n < PDIM) {
                    const int s = n - 2 * DIMC - DST;
                    const float bb = bias[n];
                    #pragma unroll
                    for (int r = 0; r < 4; ++r)
                        o_Cm[((size_t)b * LLEN + l + r) * DST + s] = v[r] + bb;
                }
            } else {
                const float bb = bias[n];
                float4 st; st.x = v[0] + bb; st.y = v[1] + bb; st.z = v[2] + bb; st.w = v[3] + bb;
                *(float4*)(o_out + ((size_t)b * DIMC + n) * LLEN + l) = st;
            }
        }
    }
}

// ---- Chunked scan, time-major bf16 dt/x ([b][l][d]) ----
// Block = 384 threads (= all d) for one (b, chunk). B (and C) staged in LDS.
// Pc/Qc/Hin layout: [b][chk][d][16].
__global__ __launch_bounds__(384)
void scan_part1(const ushort* __restrict__ dt_t, const ushort* __restrict__ x_t,
                const float* __restrict__ Bm, const float* __restrict__ A_log,
                float* __restrict__ Pc, float* __restrict__ Qc)
{
    __shared__ float Bs[CL][DST];
    const int d   = threadIdx.x;
    const int b   = blockIdx.x >> 7;          // NCH = 128
    const int chk = blockIdx.x & (NCH - 1);
    const int l0  = chk * CL;

    if (d < (CL * DST) / 4)
        ((float4*)&Bs[0][0])[d] =
            ((const float4*)(Bm + ((size_t)b * LLEN + l0) * DST))[d];

    float Av[DST];
    #pragma unroll
    for (int r = 0; r < 4; ++r) {
        float4 v = *(const float4*)(A_log + d * DST + r * 4);
        Av[r*4+0] = -__expf(v.x); Av[r*4+1] = -__expf(v.y);
        Av[r*4+2] = -__expf(v.z); Av[r*4+3] = -__expf(v.w);
    }
    __syncthreads();

    const ushort* dtp = dt_t + ((size_t)b * LLEN + l0) * DIMC + d;
    const ushort* xp  = x_t  + ((size_t)b * LLEN + l0) * DIMC + d;

    float P[DST], q[DST];
    #pragma unroll
    for (int n = 0; n < DST; ++n) { P[n] = 1.f; q[n] = 0.f; }

    for (int t0 = 0; t0 < CL; t0 += 4) {
        float dts[4], xs[4];
        #pragma unroll
        for (int j = 0; j < 4; ++j) {
            dts[j] = bf2f(dtp[(size_t)(t0 + j) * DIMC]);
            xs[j]  = bf2f(xp[(size_t)(t0 + j) * DIMC]);
        }
        #pragma unroll
        for (int j = 0; j < 4; ++j) {
            const float dt  = dts[j];
            const float dtx = dt * xs[j];
            #pragma unroll
            for (int n = 0; n < DST; ++n) {
                float a = __expf(dt * Av[n]);
                P[n] *= a;
                q[n] = fmaf(a, q[n], dtx * Bs[t0 + j][n]);
            }
        }
    }
    const size_t o = (((size_t)b * NCH + chk) * DIMC + d) * DST;
    #pragma unroll
    for (int r = 0; r < 4; ++r) {
        *(float4*)(Pc + o + r * 4) = *(float4*)&P[r * 4];
        *(float4*)(Qc + o + r * 4) = *(float4*)&q[r * 4];
    }
}

__global__ __launch_bounds__(256)
void scan_carry(const float* __restrict__ Pc, const float* __restrict__ Qc,
                float* __restrict__ Hin)
{
    const int idx = blockIdx.x * 256 + threadIdx.x;   // over B*DIMC*16
    const int bd  = idx >> 4;
    const int n   = idx & 15;
    const int b   = bd / DIMC;
    const int d   = bd - b * DIMC;
    float h = 0.f;
    for (int chk = 0; chk < NCH; ++chk) {
        const size_t o = (((size_t)b * NCH + chk) * DIMC + d) * DST + n;
        Hin[o] = h;
        h = fmaf(Pc[o], h, Qc[o]);
    }
}

// Pass 3: local rescan from Hin; y written directly as bf16 transposed [b][l][d].
__global__ __launch_bounds__(384)
void scan_part3(const ushort* __restrict__ dt_t, const ushort* __restrict__ x_t,
                const float* __restrict__ Bm, const float* __restrict__ Cm,
                const float* __restrict__ A_log, const float* __restrict__ Dv,
                const float* __restrict__ Hin, ushort* __restrict__ y_bfT)
{
    __shared__ float Bs[CL][DST];
    __shared__ float Cs[CL][DST];
    const int d   = threadIdx.x;
    const int b   = blockIdx.x >> 7;
    const int chk = blockIdx.x & (NCH - 1);
    const int l0  = chk * CL;

    if (d < 128)
        ((float4*)&Bs[0][0])[d] =
            ((const float4*)(Bm + ((size_t)b * LLEN + l0) * DST))[d];
    else if (d < 256)
        ((float4*)&Cs[0][0])[d - 128] =
            ((const float4*)(Cm + ((size_t)b * LLEN + l0) * DST))[d - 128];

    float Av[DST];
    #pragma unroll
    for (int r = 0; r < 4; ++r) {
        float4 v = *(const float4*)(A_log + d * DST + r * 4);
        Av[r*4+0] = -__expf(v.x); Av[r*4+1] = -__expf(v.y);
        Av[r*4+2] = -__expf(v.z); Av[r*4+3] = -__expf(v.w);
    }
    const float Dd = Dv[d];
    __syncthreads();

    float h[DST];
    const size_t ho = (((size_t)b * NCH + chk) * DIMC + d) * DST;
    #pragma unroll
    for (int r = 0; r < 4; ++r)
        *(float4*)&h[r * 4] = *(const float4*)(Hin + ho + r * 4);

    const ushort* dtp = dt_t + ((size_t)b * LLEN + l0) * DIMC + d;
    const ushort* xp  = x_t  + ((size_t)b * LLEN + l0) * DIMC + d;
    ushort* yp = y_bfT + ((size_t)b * LLEN + l0) * DIMC + d;

    for (int t0 = 0; t0 < CL; t0 += 4) {
        float dts[4], xs[4];
        #pragma unroll
        for (int j = 0; j < 4; ++j) {
            dts[j] = bf2f(dtp[(size_t)(t0 + j) * DIMC]);
            xs[j]  = bf2f(xp[(size_t)(t0 + j) * DIMC]);
        }
        #pragma unroll
        for (int j = 0; j < 4; ++j) {
            const float dt  = dts[j];
            const float xx  = xs[j];
            const float dtx = dt * xx;
            float yv = Dd * xx;
            #pragma unroll
            for (int n = 0; n < DST; ++n) {
                float a = __expf(dt * Av[n]);
                h[n] = fmaf(a, h[n], dtx * Bs[t0 + j][n]);
                yv = fmaf(h[n], Cs[t0 + j][n], yv);
            }
            yp[(size_t)(t0 + j) * DIMC] = f2bf(yv);
        }
    }
}

extern "C" void kernel_launch(void* const* d_in, const int* in_sizes, int n_in,
                              void* d_out, int out_size, void* d_ws, size_t ws_size,
                              hipStream_t stream)
{
    const float* x      = (const float*)d_in[0];
    const float* W_proj = (const float*)d_in[1];
    const float* b_proj = (const float*)d_in[2];
    const float* A_log  = (const float*)d_in[3];
    const float* Dv     = (const float*)d_in[4];
    const float* dt_b   = (const float*)d_in[5];
    const float* W_out  = (const float*)d_in[6];
    const float* b_out  = (const float*)d_in[7];
    float* out = (float*)d_out;

    const size_t szBD = (size_t)NB * DIMC * LLEN;          // 6,291,456
    const size_t szBC = (size_t)NB * LLEN * DST;           //   262,144
    const size_t szPQ = (size_t)NB * NCH * DIMC * DST;     // 3,145,728
    ushort* x_bf16  = (ushort*)d_ws;                       // [B][L][D] bf16 (scan x)
    ushort* dt_bf16 = x_bf16 + szBD;                       // [B][L][D] bf16
    float*  Bmw  = (float*)(dt_bf16 + szBD);
    float*  Cmw  = Bmw + szBC;
    float*  Pc   = Cmw + szBC;
    float*  Qc   = Pc + szPQ;
    float*  Hin  = Qc + szPQ;
    ushort* x_bfT = (ushort*)(Hin + szPQ);                 // [B][L][K] bf16 (GEMM1 A)
    ushort* y_bfT = x_bfT + szBD;                          // [B][L][K] bf16 (GEMM2 A)
    ushort* Wp_bf = y_bfT + szBD;                          // [832][384] bf16
    ushort* Wo_bf = Wp_bf + (size_t)832 * KDIM;            // [384][384] bf16

    cast_weights<<<(832 * KDIM + DIMC * KDIM) / 1024, 256, 0, stream>>>(
        W_proj, W_out, Wp_bf, Wo_bf);
    dim3 tg(LLEN / 64, DIMC / 64, NB);
    transpose_cast<<<tg, 256, 0, stream>>>(x, x_bfT);

    dim3 g1((NB * LLEN) / 128, (PDIM + 63) / 64);
    mfma_gemm<0><<<g1, 256, 0, stream>>>(x_bfT, Wp_bf, b_proj, dt_b,
                                         x_bf16, dt_bf16, Bmw, Cmw, nullptr);

    scan_part1<<<NB * NCH, 384, 0, stream>>>(dt_bf16, x_bf16, Bmw, A_log, Pc, Qc);
    scan_carry<<<(NB * DIMC * DST) / 256, 256, 0, stream>>>(Pc, Qc, Hin);
    scan_part3<<<NB * NCH, 384, 0, stream>>>(dt_bf16, x_bf16, Bmw, Cmw,
                                             A_log, Dv, Hin, y_bfT);

    dim3 g2((NB * LLEN) / 128, DIMC / 64);
    mfma_gemm<1><<<g2, 256, 0, stream>>>(y_bfT, Wo_bf, b_out, nullptr,
                                         nullptr, nullptr, nullptr, nullptr,
                                         out);
}